// Round 1
// baseline (500.250 us; speedup 1.0000x reference)
//
#include <hip/hip_runtime.h>
#include <hip/hip_bf16.h>

// Gemma attention decode: B=32, L=1, HID=3072, H=16, KV=8, D=256, S=2048
// All inputs/outputs fp32. Memory-bound (~1.23 GB/call -> ~195us floor).

#define SCALE_ 0.0625f   // D^-0.5 = 1/16

// workspace layout (float offsets)
// pqkv : [8][32][8192]   split-K partials of qkv gemm   (8 MB)
// xqkv : [32][8192]      final q(roped,scaled)|k(roped)|v (1 MB)
// attn : [32][4096]      attention output per head       (0.5 MB)
// po   : [16][32][3072]  split-K partials of out proj    (6 MB)
#define OFF_XQKV (8u*32u*8192u)            // 2097152
#define OFF_ATTN (OFF_XQKV + 32u*8192u)    // 2359296
#define OFF_PO   (OFF_ATTN + 32u*4096u)    // 2490368

__device__ inline void fma4(float4& a, float s, const float4& w) {
  a.x = fmaf(s, w.x, a.x); a.y = fmaf(s, w.y, a.y);
  a.z = fmaf(s, w.z, a.z); a.w = fmaf(s, w.w, a.w);
}

// ---------------------------------------------------------------------------
// Kernel A: QKV projection, split-K partials.
// grid = 32 col-tiles (of 256 cols) x 8 K-chunks (of 384) = 256 blocks
// block = 256 thr: lane(64) -> 4 consecutive cols (float4), bg(4) -> 8 batches
// Each weight element read exactly once across the grid.
__global__ __launch_bounds__(256) void qkv_partial_kernel(
    const float* __restrict__ x, const float* __restrict__ wq,
    const float* __restrict__ wk, const float* __restrict__ wv,
    float* __restrict__ pqkv) {
  const int lane = threadIdx.x & 63;
  const int bg   = threadIdx.x >> 6;       // 0..3
  const int ctile = blockIdx.x & 31;       // 0..31
  const int kc    = blockIdx.x >> 5;       // 0..7
  const int n = ctile * 256 + lane * 4;    // global output column (of 8192)

  const float* w; int stride, nn;
  if (n < 4096)      { w = wq; stride = 4096; nn = n; }
  else if (n < 6144) { w = wk; stride = 2048; nn = n - 4096; }
  else               { w = wv; stride = 2048; nn = n - 6144; }

  const float* wb = w + (size_t)(kc * 384) * stride + nn;
  const float* xb = x + (size_t)(bg * 8) * 3072 + kc * 384;

  float4 acc[8];
#pragma unroll
  for (int j = 0; j < 8; ++j) acc[j] = make_float4(0.f, 0.f, 0.f, 0.f);

  for (int k = 0; k < 384; k += 4) {
    float4 w0 = *(const float4*)(wb + (size_t)(k + 0) * stride);
    float4 w1 = *(const float4*)(wb + (size_t)(k + 1) * stride);
    float4 w2 = *(const float4*)(wb + (size_t)(k + 2) * stride);
    float4 w3 = *(const float4*)(wb + (size_t)(k + 3) * stride);
#pragma unroll
    for (int j = 0; j < 8; ++j) {
      float4 xv = *(const float4*)(xb + j * 3072 + k);
      fma4(acc[j], xv.x, w0);
      fma4(acc[j], xv.y, w1);
      fma4(acc[j], xv.z, w2);
      fma4(acc[j], xv.w, w3);
    }
  }
#pragma unroll
  for (int j = 0; j < 8; ++j) {
    *(float4*)(pqkv + ((size_t)kc * 32 + bg * 8 + j) * 8192 + n) = acc[j];
  }
}

// ---------------------------------------------------------------------------
// Kernel B: reduce split-K partials + RoPE (q,k) + fold SCALE into q.
// work item space per batch: 2048 q-pairs + 1024 k-pairs + 2048 v elems = 5120
// grid = 640 x 256 = 163840 = 32*5120
__global__ __launch_bounds__(256) void reduce_rope_kernel(
    const float* __restrict__ pqkv, const float* __restrict__ fcos,
    const float* __restrict__ fsin, float* __restrict__ xqkv) {
  const int w = blockIdx.x * 256 + threadIdx.x;
  const int b = w / 5120;
  const int r = w - b * 5120;
  const float* pb = pqkv + (size_t)b * 8192;
  float* ob = xqkv + (size_t)b * 8192;

  if (r < 3072) {
    // RoPE pair
    int n1, d;
    const bool isq = (r < 2048);
    if (isq) { int h = r >> 7; d = r & 127; n1 = h * 256 + d; }
    else     { int idx = r - 2048; int kvh = idx >> 7; d = idx & 127;
               n1 = 4096 + kvh * 256 + d; }
    const int n2 = n1 + 128;
    float xr = 0.f, xi = 0.f;
#pragma unroll
    for (int kc = 0; kc < 8; ++kc) {
      xr += pb[(size_t)kc * 262144 + n1];
      xi += pb[(size_t)kc * 262144 + n2];
    }
    const float c = fcos[b * 128 + d];
    const float s = fsin[b * 128 + d];
    float o1 = xr * c - xi * s;
    float o2 = xr * s + xi * c;
    if (isq) { o1 *= SCALE_; o2 *= SCALE_; }
    ob[n1] = o1;
    ob[n2] = o2;
  } else {
    const int nn = 6144 + (r - 3072);
    float v = 0.f;
#pragma unroll
    for (int kc = 0; kc < 8; ++kc) v += pb[(size_t)kc * 262144 + nn];
    ob[nn] = v;
  }
}

// ---------------------------------------------------------------------------
// Kernel C: attention. grid = 256 blocks (b*8+kv), block = 1024 thr (16 waves)
// wave handles rows s = wave, wave+16, ...; lane -> float4 of D (lane*4)
__global__ __launch_bounds__(1024) void attn_kernel(
    const float* __restrict__ xqkv, const float* __restrict__ cache_k,
    const float* __restrict__ cache_v, const float* __restrict__ mask,
    const int* __restrict__ posp, float* __restrict__ attn_out) {
  __shared__ float sc[2][2048];      // scores -> probs
  __shared__ float accbuf[16][512];  // per-wave PV partials [wave][g*256+d]
  __shared__ float red[16];
  __shared__ float gtmp;
  __shared__ float ginv[2];

  const int tid = threadIdx.x, lane = tid & 63, wv = tid >> 6;
  const int b = blockIdx.x >> 3, kv = blockIdx.x & 7;
  const int pos = posp[0];

  const float* xb = xqkv + (size_t)b * 8192;
  const float4 q0 = *(const float4*)(xb + (kv * 2 + 0) * 256 + lane * 4);
  const float4 q1 = *(const float4*)(xb + (kv * 2 + 1) * 256 + lane * 4);
  const float* knew = xb + 4096 + kv * 256;
  const float* vnew = xb + 6144 + kv * 256;
  const size_t base = ((size_t)b * 8 + kv) * 2048 * 256;
  const float* mrow = mask + (size_t)b * 2048;

  // phase 1: scores
  for (int s = wv; s < 2048; s += 16) {
    const float* kr = (s == pos) ? knew : (cache_k + base + (size_t)s * 256);
    const float4 k4 = *(const float4*)(kr + lane * 4);
    float d0 = q0.x * k4.x + q0.y * k4.y + q0.z * k4.z + q0.w * k4.w;
    float d1 = q1.x * k4.x + q1.y * k4.y + q1.z * k4.z + q1.w * k4.w;
#pragma unroll
    for (int off = 32; off > 0; off >>= 1) {
      d0 += __shfl_xor(d0, off);
      d1 += __shfl_xor(d1, off);
    }
    if (lane == 0) {
      const float mk = mrow[s];
      sc[0][s] = d0 + mk;
      sc[1][s] = d1 + mk;
    }
  }
  __syncthreads();

  // phase 2: softmax (per g)
  for (int g = 0; g < 2; ++g) {
    const float v0 = sc[g][tid], v1 = sc[g][tid + 1024];
    float m = fmaxf(v0, v1);
#pragma unroll
    for (int off = 32; off > 0; off >>= 1) m = fmaxf(m, __shfl_xor(m, off));
    if (lane == 0) red[wv] = m;
    __syncthreads();
    if (tid < 64) {
      float t = (lane < 16) ? red[lane] : -3.0e38f;
#pragma unroll
      for (int off = 8; off > 0; off >>= 1) t = fmaxf(t, __shfl_xor(t, off));
      if (lane == 0) gtmp = t;
    }
    __syncthreads();
    const float mg = gtmp;
    const float e0 = __expf(v0 - mg), e1 = __expf(v1 - mg);
    sc[g][tid] = e0;
    sc[g][tid + 1024] = e1;
    float sm = e0 + e1;
#pragma unroll
    for (int off = 32; off > 0; off >>= 1) sm += __shfl_xor(sm, off);
    if (lane == 0) red[wv] = sm;
    __syncthreads();
    if (tid < 64) {
      float t = (lane < 16) ? red[lane] : 0.f;
#pragma unroll
      for (int off = 8; off > 0; off >>= 1) t += __shfl_xor(t, off);
      if (lane == 0) ginv[g] = 1.f / t;
    }
    __syncthreads();
  }

  // phase 3: PV
  float4 a0 = make_float4(0.f, 0.f, 0.f, 0.f);
  float4 a1 = make_float4(0.f, 0.f, 0.f, 0.f);
  for (int s = wv; s < 2048; s += 16) {
    const float* vr = (s == pos) ? vnew : (cache_v + base + (size_t)s * 256);
    const float4 v4 = *(const float4*)(vr + lane * 4);
    const float p0 = sc[0][s], p1 = sc[1][s];
    fma4(a0, p0, v4);
    fma4(a1, p1, v4);
  }
  *(float4*)(&accbuf[wv][lane * 4]) = a0;
  *(float4*)(&accbuf[wv][256 + lane * 4]) = a1;
  __syncthreads();
  if (tid < 512) {
    const int g = tid >> 8, d = tid & 255;
    float t = 0.f;
#pragma unroll
    for (int w2 = 0; w2 < 16; ++w2) t += accbuf[w2][g * 256 + d];
    attn_out[(size_t)b * 4096 + (kv * 2 + g) * 256 + d] = t * ginv[g];
  }
}

// ---------------------------------------------------------------------------
// Kernel D: output projection partials. M=32, K=4096, N=3072, split-K=16.
// grid = 12 col-tiles x 16 K-chunks = 192 blocks; block like kernel A.
__global__ __launch_bounds__(256) void oproj_partial_kernel(
    const float* __restrict__ attn, const float* __restrict__ wo,
    float* __restrict__ po) {
  const int lane = threadIdx.x & 63;
  const int bg   = threadIdx.x >> 6;
  const int ctile = blockIdx.x % 12;
  const int kc    = blockIdx.x / 12;      // 0..15, chunk of 256
  const int n = ctile * 256 + lane * 4;

  const float* wb = wo + (size_t)(kc * 256) * 3072 + n;
  const float* xb = attn + (size_t)(bg * 8) * 4096 + kc * 256;

  float4 acc[8];
#pragma unroll
  for (int j = 0; j < 8; ++j) acc[j] = make_float4(0.f, 0.f, 0.f, 0.f);

  for (int k = 0; k < 256; k += 4) {
    float4 w0 = *(const float4*)(wb + (size_t)(k + 0) * 3072);
    float4 w1 = *(const float4*)(wb + (size_t)(k + 1) * 3072);
    float4 w2 = *(const float4*)(wb + (size_t)(k + 2) * 3072);
    float4 w3 = *(const float4*)(wb + (size_t)(k + 3) * 3072);
#pragma unroll
    for (int j = 0; j < 8; ++j) {
      float4 xv = *(const float4*)(xb + j * 4096 + k);
      fma4(acc[j], xv.x, w0);
      fma4(acc[j], xv.y, w1);
      fma4(acc[j], xv.z, w2);
      fma4(acc[j], xv.w, w3);
    }
  }
#pragma unroll
  for (int j = 0; j < 8; ++j) {
    *(float4*)(po + ((size_t)kc * 32 + bg * 8 + j) * 3072 + n) = acc[j];
  }
}

// ---------------------------------------------------------------------------
// Kernel E: sum the 16 out-proj partials -> d_out (fully written every call).
__global__ __launch_bounds__(256) void finalize_kernel(
    const float* __restrict__ po, float* __restrict__ out) {
  const int i = blockIdx.x * 256 + threadIdx.x;  // < 24576 float4s
  const float4* p = (const float4*)po;
  float4 acc = make_float4(0.f, 0.f, 0.f, 0.f);
#pragma unroll
  for (int kc = 0; kc < 16; ++kc) {
    const float4 v = p[(size_t)kc * 24576 + i];
    acc.x += v.x; acc.y += v.y; acc.z += v.z; acc.w += v.w;
  }
  ((float4*)out)[i] = acc;
}

// ---------------------------------------------------------------------------
extern "C" void kernel_launch(void* const* d_in, const int* in_sizes, int n_in,
                              void* d_out, int out_size, void* d_ws, size_t ws_size,
                              hipStream_t stream) {
  (void)in_sizes; (void)n_in; (void)out_size; (void)ws_size;
  const float* x    = (const float*)d_in[0];
  const float* fcos = (const float*)d_in[1];
  const float* fsin = (const float*)d_in[2];
  const float* mask = (const float*)d_in[3];
  const float* ck   = (const float*)d_in[4];
  const float* cv   = (const float*)d_in[5];
  const float* wq   = (const float*)d_in[6];
  const float* wk   = (const float*)d_in[7];
  const float* wv   = (const float*)d_in[8];
  const float* wo   = (const float*)d_in[9];
  const int*   pos  = (const int*)d_in[10];

  float* ws   = (float*)d_ws;            // needs ~15.5 MB
  float* pqkv = ws;
  float* xqkv = ws + OFF_XQKV;
  float* attn = ws + OFF_ATTN;
  float* po   = ws + OFF_PO;
  float* out  = (float*)d_out;

  qkv_partial_kernel<<<256, 256, 0, stream>>>(x, wq, wk, wv, pqkv);
  reduce_rope_kernel<<<640, 256, 0, stream>>>(pqkv, fcos, fsin, xqkv);
  attn_kernel<<<256, 1024, 0, stream>>>(xqkv, ck, cv, mask, pos, attn);
  oproj_partial_kernel<<<192, 256, 0, stream>>>(attn, wo, po);
  finalize_kernel<<<96, 256, 0, stream>>>(po, out);
}

// Round 2
// 328.166 us; speedup vs baseline: 1.5244x; 1.5244x over previous
//
#include <hip/hip_runtime.h>
#include <hip/hip_bf16.h>

// Gemma attention decode: B=32, L=1, HID=3072, H=16, KV=8, D=256, S=2048
// All fp32. Memory-bound: ~1.23 GB/call -> ~195us floor at 6.3 TB/s.

#define SCALE_ 0.0625f   // D^-0.5 = 1/16

// workspace layout (float offsets), total 16.3 MB (same as R1 proven fit)
// pqkv : [8][32][8192]  split-K partials of qkv gemm (8 MB)  -- dead after reduce_rope
//   opart (alias pqkv+0)      : [32][8][8][2][256] = 1,048,576 f
//   ml    (alias pqkv+1048576): [32][8][8][2] float2 = 16,384 f
// xqkv : [32][8192]  q(roped,scaled)|k(roped)|v
// attn : [32][4096]
// po   : [16][32][3072]
#define OFF_XQKV (8u*32u*8192u)            // 2097152
#define OFF_ATTN (OFF_XQKV + 32u*8192u)    // 2359296
#define OFF_PO   (OFF_ATTN + 32u*4096u)    // 2490368
#define OFF_ML   (1048576u)

__device__ inline void fma4(float4& a, float s, const float4& w) {
  a.x = fmaf(s, w.x, a.x); a.y = fmaf(s, w.y, a.y);
  a.z = fmaf(s, w.z, a.z); a.w = fmaf(s, w.w, a.w);
}
__device__ inline float dot4(const float4& a, const float4& b) {
  return a.x * b.x + a.y * b.y + a.z * b.z + a.w * b.w;
}

// ---------------------------------------------------------------------------
// Kernel A: QKV projection, split-K partials.
// grid = 32 col-tiles (256 cols) x 8 K-chunks (384 rows) = 256 blocks
// block = 512 thr (8 waves): lane -> 4 cols (float4), bg(8) -> 4 batches each
// Each weight element fetched from HBM exactly once across the grid.
__global__ __launch_bounds__(512) void qkv_partial_kernel(
    const float* __restrict__ x, const float* __restrict__ wq,
    const float* __restrict__ wk, const float* __restrict__ wv,
    float* __restrict__ pqkv) {
  const int lane = threadIdx.x & 63;
  const int bg   = threadIdx.x >> 6;       // 0..7 -> batches bg*4..bg*4+3
  const int ctile = blockIdx.x & 31;
  const int kc    = blockIdx.x >> 5;       // 0..7
  const int n = ctile * 256 + lane * 4;    // output column (of 8192)

  const float* w; int stride, nn;
  if (n < 4096)      { w = wq; stride = 4096; nn = n; }
  else if (n < 6144) { w = wk; stride = 2048; nn = n - 4096; }
  else               { w = wv; stride = 2048; nn = n - 6144; }

  const float* wb = w + (size_t)(kc * 384) * stride + nn;
  const float* xb = x + (size_t)(bg * 4) * 3072 + kc * 384;

  float4 acc[4];
#pragma unroll
  for (int j = 0; j < 4; ++j) acc[j] = make_float4(0.f, 0.f, 0.f, 0.f);

  for (int k = 0; k < 384; k += 4) {
    float4 w0 = *(const float4*)(wb + (size_t)(k + 0) * stride);
    float4 w1 = *(const float4*)(wb + (size_t)(k + 1) * stride);
    float4 w2 = *(const float4*)(wb + (size_t)(k + 2) * stride);
    float4 w3 = *(const float4*)(wb + (size_t)(k + 3) * stride);
#pragma unroll
    for (int j = 0; j < 4; ++j) {
      float4 xv = *(const float4*)(xb + j * 3072 + k);
      fma4(acc[j], xv.x, w0);
      fma4(acc[j], xv.y, w1);
      fma4(acc[j], xv.z, w2);
      fma4(acc[j], xv.w, w3);
    }
  }
#pragma unroll
  for (int j = 0; j < 4; ++j) {
    *(float4*)(pqkv + ((size_t)kc * 32 + bg * 4 + j) * 8192 + n) = acc[j];
  }
}

// ---------------------------------------------------------------------------
// Kernel B: reduce split-K partials + RoPE (q,k) + fold SCALE into q.
__global__ __launch_bounds__(256) void reduce_rope_kernel(
    const float* __restrict__ pqkv, const float* __restrict__ fcos,
    const float* __restrict__ fsin, float* __restrict__ xqkv) {
  const int w = blockIdx.x * 256 + threadIdx.x;
  const int b = w / 5120;
  const int r = w - b * 5120;
  const float* pb = pqkv + (size_t)b * 8192;
  float* ob = xqkv + (size_t)b * 8192;

  if (r < 3072) {
    int n1, d;
    const bool isq = (r < 2048);
    if (isq) { int h = r >> 7; d = r & 127; n1 = h * 256 + d; }
    else     { int idx = r - 2048; int kvh = idx >> 7; d = idx & 127;
               n1 = 4096 + kvh * 256 + d; }
    const int n2 = n1 + 128;
    float xr = 0.f, xi = 0.f;
#pragma unroll
    for (int kc = 0; kc < 8; ++kc) {
      xr += pb[(size_t)kc * 262144 + n1];
      xi += pb[(size_t)kc * 262144 + n2];
    }
    const float c = fcos[b * 128 + d];
    const float s = fsin[b * 128 + d];
    float o1 = xr * c - xi * s;
    float o2 = xr * s + xi * c;
    if (isq) { o1 *= SCALE_; o2 *= SCALE_; }
    ob[n1] = o1;
    ob[n2] = o2;
  } else {
    const int nn = 6144 + (r - 3072);
    float v = 0.f;
#pragma unroll
    for (int kc = 0; kc < 8; ++kc) v += pb[(size_t)kc * 262144 + nn];
    ob[nn] = v;
  }
}

// ---------------------------------------------------------------------------
// Kernel C: flash-decode attention chunk.
// grid = 2048 blocks: b(32) x kv(8) x chunk(8 of 256 rows); block 256 thr.
// Phase 1: 2 K-rows per wave pass (32 lanes/row, 8 floats/lane), 5 shfl levels.
// Emits unnormalized PV partial + (m,l) per chunk; combine kernel merges.
__global__ __launch_bounds__(256) void attn_chunk_kernel(
    const float* __restrict__ xqkv, const float* __restrict__ cache_k,
    const float* __restrict__ cache_v, const float* __restrict__ mask,
    const int* __restrict__ posp, float* __restrict__ opart,
    float* __restrict__ ml) {
  __shared__ float sc[2][256];
  __shared__ float accbuf[4][512];
  __shared__ float red0[4], red1[4];

  const int tid = threadIdx.x, lane = tid & 63, wv = tid >> 6;
  const int c  = blockIdx.x & 7;
  const int kv = (blockIdx.x >> 3) & 7;
  const int b  = blockIdx.x >> 6;
  const int pos = posp[0];
  const int s0 = c * 256;

  const float* xb = xqkv + (size_t)b * 8192;
  const float* knew = xb + 4096 + kv * 256;
  const float* vnew = xb + 6144 + kv * 256;
  const size_t base = ((size_t)b * 8 + kv) * 2048 * 256;
  const float* mrow = mask + (size_t)b * 2048;

  // q fragments for phase 1: 8 floats at dbase (same for both lane-halves)
  const int dbase = (lane & 31) * 8;
  const float4 qa0 = *(const float4*)(xb + (kv * 2 + 0) * 256 + dbase);
  const float4 qa1 = *(const float4*)(xb + (kv * 2 + 0) * 256 + dbase + 4);
  const float4 qb0 = *(const float4*)(xb + (kv * 2 + 1) * 256 + dbase);
  const float4 qb1 = *(const float4*)(xb + (kv * 2 + 1) * 256 + dbase + 4);

  // phase 1: scores. Each wave pass covers 2 rows (one per 32-lane half).
  for (int i = 0; i < 32; ++i) {
    const int sp = wv + 4 * i;                 // pair index 0..127
    const int sl = sp * 2 + (lane >> 5);       // local row 0..255
    const int s  = s0 + sl;
    const float* kr = (s == pos) ? knew : (cache_k + base + (size_t)s * 256);
    const float4 ka = *(const float4*)(kr + dbase);
    const float4 kb = *(const float4*)(kr + dbase + 4);
    float d0 = dot4(qa0, ka) + dot4(qa1, kb);
    float d1 = dot4(qb0, ka) + dot4(qb1, kb);
#pragma unroll
    for (int off = 16; off > 0; off >>= 1) {
      d0 += __shfl_xor(d0, off);
      d1 += __shfl_xor(d1, off);
    }
    if ((lane & 31) == 0) {
      const float mk = mrow[s];
      sc[0][sl] = d0 + mk;
      sc[1][sl] = d1 + mk;
    }
  }
  __syncthreads();

  // chunk-local softmax stats (row <-> tid)
  const float v0 = sc[0][tid], v1 = sc[1][tid];
  float m0 = v0, m1 = v1;
#pragma unroll
  for (int off = 32; off > 0; off >>= 1) {
    m0 = fmaxf(m0, __shfl_xor(m0, off));
    m1 = fmaxf(m1, __shfl_xor(m1, off));
  }
  if (lane == 0) { red0[wv] = m0; red1[wv] = m1; }
  __syncthreads();
  m0 = fmaxf(fmaxf(red0[0], red0[1]), fmaxf(red0[2], red0[3]));
  m1 = fmaxf(fmaxf(red1[0], red1[1]), fmaxf(red1[2], red1[3]));
  const float e0 = __expf(v0 - m0), e1 = __expf(v1 - m1);
  sc[0][tid] = e0;
  sc[1][tid] = e1;
  float l0 = e0, l1 = e1;
#pragma unroll
  for (int off = 32; off > 0; off >>= 1) {
    l0 += __shfl_xor(l0, off);
    l1 += __shfl_xor(l1, off);
  }
  __syncthreads();              // make sure everyone read red before rewrite
  if (lane == 0) { red0[wv] = l0; red1[wv] = l1; }
  __syncthreads();
  if (tid == 0) {
    l0 = red0[0] + red0[1] + red0[2] + red0[3];
    l1 = red1[0] + red1[1] + red1[2] + red1[3];
    float2* mlp = (float2*)ml;
    const int mlbase = (((b * 8 + kv) * 8) + c) * 2;
    mlp[mlbase + 0] = make_float2(m0, l0);
    mlp[mlbase + 1] = make_float2(m1, l1);
  }

  // phase 3: PV partial. lane -> d = lane*4; wave -> rows wv+4i.
  float4 a0 = make_float4(0.f, 0.f, 0.f, 0.f);
  float4 a1 = make_float4(0.f, 0.f, 0.f, 0.f);
  for (int i = 0; i < 64; ++i) {
    const int sl = wv + 4 * i;
    const int s = s0 + sl;
    const float* vr = (s == pos) ? vnew : (cache_v + base + (size_t)s * 256);
    const float4 v4 = *(const float4*)(vr + lane * 4);
    fma4(a0, sc[0][sl], v4);
    fma4(a1, sc[1][sl], v4);
  }
  *(float4*)(&accbuf[wv][lane * 4]) = a0;
  *(float4*)(&accbuf[wv][256 + lane * 4]) = a1;
  __syncthreads();
  const size_t obase = (size_t)((b * 8 + kv) * 8 + c) * 512;
  for (int t = tid; t < 512; t += 256) {
    opart[obase + t] = accbuf[0][t] + accbuf[1][t] + accbuf[2][t] + accbuf[3][t];
  }
}

// ---------------------------------------------------------------------------
// Kernel C2: combine the 8 chunk partials -> attn output per head.
// grid 512 x 256: idx -> (b,kv,g,d)
__global__ __launch_bounds__(256) void attn_combine_kernel(
    const float* __restrict__ opart, const float* __restrict__ ml,
    float* __restrict__ attn_out) {
  const int idx = blockIdx.x * 256 + threadIdx.x;  // < 131072
  const int d = idx & 255;
  const int g = (idx >> 8) & 1;
  const int kvb = idx >> 9;                        // b*8+kv
  const float2* mlp = (const float2*)ml;

  float2 mls[8];
  float M = -3.4e38f;
#pragma unroll
  for (int c = 0; c < 8; ++c) {
    mls[c] = mlp[(kvb * 8 + c) * 2 + g];
    M = fmaxf(M, mls[c].x);
  }
  float L = 0.f, O = 0.f;
#pragma unroll
  for (int c = 0; c < 8; ++c) {
    const float w = __expf(mls[c].x - M);
    L = fmaf(mls[c].y, w, L);
    O = fmaf(opart[(size_t)(kvb * 8 + c) * 512 + g * 256 + d], w, O);
  }
  const int b = kvb >> 3, kv = kvb & 7;
  attn_out[(size_t)b * 4096 + (kv * 2 + g) * 256 + d] = O / L;
}

// ---------------------------------------------------------------------------
// Kernel D: output projection partials. M=32, K=4096, N=3072, split-K=16.
// grid = 12 col-tiles x 16 K-chunks = 192 blocks; block 512 thr (8 waves).
__global__ __launch_bounds__(512) void oproj_partial_kernel(
    const float* __restrict__ attn, const float* __restrict__ wo,
    float* __restrict__ po) {
  const int lane = threadIdx.x & 63;
  const int bg   = threadIdx.x >> 6;      // 0..7 -> batches bg*4..bg*4+3
  const int ctile = blockIdx.x % 12;
  const int kc    = blockIdx.x / 12;      // 0..15, chunk of 256
  const int n = ctile * 256 + lane * 4;

  const float* wb = wo + (size_t)(kc * 256) * 3072 + n;
  const float* xb = attn + (size_t)(bg * 4) * 4096 + kc * 256;

  float4 acc[4];
#pragma unroll
  for (int j = 0; j < 4; ++j) acc[j] = make_float4(0.f, 0.f, 0.f, 0.f);

  for (int k = 0; k < 256; k += 4) {
    float4 w0 = *(const float4*)(wb + (size_t)(k + 0) * 3072);
    float4 w1 = *(const float4*)(wb + (size_t)(k + 1) * 3072);
    float4 w2 = *(const float4*)(wb + (size_t)(k + 2) * 3072);
    float4 w3 = *(const float4*)(wb + (size_t)(k + 3) * 3072);
#pragma unroll
    for (int j = 0; j < 4; ++j) {
      float4 xv = *(const float4*)(xb + j * 4096 + k);
      fma4(acc[j], xv.x, w0);
      fma4(acc[j], xv.y, w1);
      fma4(acc[j], xv.z, w2);
      fma4(acc[j], xv.w, w3);
    }
  }
#pragma unroll
  for (int j = 0; j < 4; ++j) {
    *(float4*)(po + ((size_t)kc * 32 + bg * 4 + j) * 3072 + n) = acc[j];
  }
}

// ---------------------------------------------------------------------------
// Kernel E: sum the 16 out-proj partials -> d_out.
__global__ __launch_bounds__(256) void finalize_kernel(
    const float* __restrict__ po, float* __restrict__ out) {
  const int i = blockIdx.x * 256 + threadIdx.x;  // < 24576 float4s
  const float4* p = (const float4*)po;
  float4 acc = make_float4(0.f, 0.f, 0.f, 0.f);
#pragma unroll
  for (int kc = 0; kc < 16; ++kc) {
    const float4 v = p[(size_t)kc * 24576 + i];
    acc.x += v.x; acc.y += v.y; acc.z += v.z; acc.w += v.w;
  }
  ((float4*)out)[i] = acc;
}

// ---------------------------------------------------------------------------
extern "C" void kernel_launch(void* const* d_in, const int* in_sizes, int n_in,
                              void* d_out, int out_size, void* d_ws, size_t ws_size,
                              hipStream_t stream) {
  (void)in_sizes; (void)n_in; (void)out_size; (void)ws_size;
  const float* x    = (const float*)d_in[0];
  const float* fcos = (const float*)d_in[1];
  const float* fsin = (const float*)d_in[2];
  const float* mask = (const float*)d_in[3];
  const float* ck   = (const float*)d_in[4];
  const float* cv   = (const float*)d_in[5];
  const float* wq   = (const float*)d_in[6];
  const float* wk   = (const float*)d_in[7];
  const float* wv   = (const float*)d_in[8];
  const float* wo   = (const float*)d_in[9];
  const int*   pos  = (const int*)d_in[10];

  float* ws    = (float*)d_ws;
  float* pqkv  = ws;                 // dead after reduce_rope
  float* opart = ws;                 // aliases pqkv (used after it's dead)
  float* ml    = ws + OFF_ML;        // aliases pqkv tail
  float* xqkv  = ws + OFF_XQKV;
  float* attn  = ws + OFF_ATTN;
  float* po    = ws + OFF_PO;
  float* out   = (float*)d_out;

  qkv_partial_kernel<<<256, 512, 0, stream>>>(x, wq, wk, wv, pqkv);
  reduce_rope_kernel<<<640, 256, 0, stream>>>(pqkv, fcos, fsin, xqkv);
  attn_chunk_kernel<<<2048, 256, 0, stream>>>(xqkv, ck, cv, mask, pos, opart, ml);
  attn_combine_kernel<<<512, 256, 0, stream>>>(opart, ml, attn);
  oproj_partial_kernel<<<192, 512, 0, stream>>>(attn, wo, po);
  finalize_kernel<<<96, 256, 0, stream>>>(po, out);
}